// Round 5
// baseline (5131.725 us; speedup 1.0000x reference)
//
#include <hip/hip_runtime.h>
#include <hip/hip_bf16.h>
#include <cstddef>

// Problem constants
#define B_   1024
#define C_   3
#define NP_  10
#define PL_  100
#define D_   768
#define H_   12
#define L_   12
#define N_   12   // NP + 2
#define HD_  64

typedef __attribute__((ext_vector_type(8))) short short8;   // 8 x bf16 (4 VGPRs)
typedef __attribute__((ext_vector_type(4))) float float4v;  // 4 x f32 acc

__device__ __forceinline__ ushort f2bf(float x) {
    __hip_bfloat16 h = __float2bfloat16(x);
    return *(ushort*)&h;
}
__device__ __forceinline__ float bf2f(ushort u) {
    union { unsigned u32; float f; } x; x.u32 = ((unsigned)u) << 16; return x.f;
}

// async global->LDS 16B copy: per-lane global addr, wave-uniform LDS base,
// HW writes lane i at base + i*16.
__device__ __forceinline__ void async_cp16(const ushort* g, ushort* lds) {
    __builtin_amdgcn_global_load_lds(
        (const __attribute__((address_space(1))) unsigned int*)g,
        (__attribute__((address_space(3))) unsigned int*)lds, 16, 0, 0);
}

// ---------------------------------------------------------------------------
// Block-wide reduction of two floats across 256 threads (4 waves of 64).
// ---------------------------------------------------------------------------
__device__ __forceinline__ void block_reduce2(float& a, float& b) {
    __shared__ float sa[4], sb[4];
#pragma unroll
    for (int off = 32; off > 0; off >>= 1) {
        a += __shfl_down(a, off);
        b += __shfl_down(b, off);
    }
    int wid = threadIdx.x >> 6, lane = threadIdx.x & 63;
    __syncthreads();
    if (lane == 0) { sa[wid] = a; sb[wid] = b; }
    __syncthreads();
    if (threadIdx.x == 0) {
        float ta = 0.f, tb = 0.f;
#pragma unroll
        for (int i = 0; i < 4; ++i) { ta += sa[i]; tb += sb[i]; }
        sa[0] = ta; sb[0] = tb;
    }
    __syncthreads();
    a = sa[0]; b = sb[0];
}

// ---------------------------------------------------------------------------
// fp32 tiled GEMM — only for the tiny stats/topo embeds (K=56/24).
// ---------------------------------------------------------------------------
#define BM 64
#define BN 64
#define BK 16

__global__ __launch_bounds__(256) void gemm_kernel(
    const float* __restrict__ A, const float* __restrict__ W,
    const float* __restrict__ bias, float* __restrict__ C,
    int M, int N, int K)
{
    __shared__ float As[BK][BM];
    __shared__ float Ws[BK][BN];

    const int tid = threadIdx.x;
    const int tx = tid & 15, ty = tid >> 4;
    const int m0 = blockIdx.y * BM, n0 = blockIdx.x * BN;

    float acc[4][4] = {};

    const int am  = tid & 63;
    const int akq = tid >> 6;
    const int wn  = (tid & 15) * 4;
    const int wk  = tid >> 4;

    for (int k0 = 0; k0 < K; k0 += BK) {
        float4 av = make_float4(0.f, 0.f, 0.f, 0.f);
        int gm = m0 + am;
        int gk = k0 + akq * 4;
        if (gm < M && gk + 3 < K)
            av = *(const float4*)(A + (size_t)gm * K + gk);
        else if (gm < M) {
            float tmp[4] = {0.f, 0.f, 0.f, 0.f};
            for (int i = 0; i < 4; ++i)
                if (gk + i < K) tmp[i] = A[(size_t)gm * K + gk + i];
            av = make_float4(tmp[0], tmp[1], tmp[2], tmp[3]);
        }
        As[akq * 4 + 0][am] = av.x;
        As[akq * 4 + 1][am] = av.y;
        As[akq * 4 + 2][am] = av.z;
        As[akq * 4 + 3][am] = av.w;

        float4 wv = make_float4(0.f, 0.f, 0.f, 0.f);
        int gkw = k0 + wk, gn = n0 + wn;
        if (gkw < K && gn < N)
            wv = *(const float4*)(W + (size_t)gkw * N + gn);
        *(float4*)&Ws[wk][wn] = wv;

        __syncthreads();

#pragma unroll
        for (int kk = 0; kk < BK; ++kk) {
            float4 a = *(const float4*)&As[kk][ty * 4];
            float4 b = *(const float4*)&Ws[kk][tx * 4];
            acc[0][0] += a.x * b.x; acc[0][1] += a.x * b.y; acc[0][2] += a.x * b.z; acc[0][3] += a.x * b.w;
            acc[1][0] += a.y * b.x; acc[1][1] += a.y * b.y; acc[1][2] += a.y * b.z; acc[1][3] += a.y * b.w;
            acc[2][0] += a.z * b.x; acc[2][1] += a.z * b.y; acc[2][2] += a.z * b.z; acc[2][3] += a.z * b.w;
            acc[3][0] += a.w * b.x; acc[3][1] += a.w * b.y; acc[3][2] += a.w * b.z; acc[3][3] += a.w * b.w;
        }
        __syncthreads();
    }

#pragma unroll
    for (int i = 0; i < 4; ++i) {
        int row = m0 + ty * 4 + i;
        if (row >= M) continue;
#pragma unroll
        for (int j = 0; j < 4; ++j) {
            int col = n0 + tx * 4 + j;
            if (col >= N) continue;
            C[(size_t)row * N + col] = acc[i][j] + bias[col];
        }
    }
}

// ---------------------------------------------------------------------------
// Batched weight convert+transpose: fp32 [K,N] -> bf16 [Npad, Kpad]
// (zero-filled in [N,Npad) rows and [K,Kpad) cols). blockIdx.z = batch.
// ---------------------------------------------------------------------------
__global__ __launch_bounds__(256) void transpose_bf16_b(
    const float* __restrict__ in, ushort* __restrict__ out,
    int K, int N, int Kpad, int Npad, size_t in_stride, size_t out_stride)
{
    __shared__ float t[32][33];
    const float* inz = in + (size_t)blockIdx.z * in_stride;
    ushort* outz = out + (size_t)blockIdx.z * out_stride;
    const int tx = threadIdx.x & 31, ty = threadIdx.x >> 5;  // 32 x 8
    const int k0 = blockIdx.y * 32, n0 = blockIdx.x * 32;
#pragma unroll
    for (int i = 0; i < 4; ++i) {
        int k = k0 + ty + i * 8, n = n0 + tx;
        t[ty + i * 8][tx] = (k < K && n < N) ? inz[(size_t)k * N + n] : 0.f;
    }
    __syncthreads();
#pragma unroll
    for (int i = 0; i < 4; ++i) {
        int n = n0 + ty + i * 8, k = k0 + tx;
        if (n < Npad && k < Kpad)
            outz[(size_t)n * Kpad + k] = f2bf(t[tx][ty + i * 8]);
    }
}

// ---------------------------------------------------------------------------
// Patch gather -> bf16 A matrix [B*NP, 320] (zero-padded cols 300..319).
// ---------------------------------------------------------------------------
__global__ __launch_bounds__(256) void patch_gather(
    const float* __restrict__ patches, ushort* __restrict__ PB)
{
    int idx = blockIdx.x * 256 + threadIdx.x;   // B*NP*320
    int row = idx / 320, col = idx % 320;
    ushort v = 0;
    if (col < 300) {
        int bb = row / 10, n = row % 10, c = col / 100, p = col % 100;
        v = f2bf(patches[(size_t)((bb * 3 + c) * 10 + n) * 100 + p]);
    }
    PB[idx] = v;
}

// ---------------------------------------------------------------------------
// bf16 MFMA GEMM: out[M,N] = A[M,K] @ Wt[Npad,K]^T + bias (+res)
// 128x128 tile, BK=64, global_load_lds width=16 staging, XOR-8 chunk swizzle
// (chunk c of row r lives at LDS chunk c^(r&7)) -> conflict-free ds_read_b128.
// Requirements: M % 128 == 0, K % 64 == 0, Wt has >= gridDim.x*128 rows
// (zero-padded). GUARD: store-guard col < N (only needed when N % 128 != 0).
// ---------------------------------------------------------------------------
template<bool GUARD>
__global__ __launch_bounds__(256) void mfma_gemm(
    const ushort* __restrict__ A, const ushort* __restrict__ Wt,
    const float* __restrict__ bias, const float* __restrict__ res,
    void* __restrict__ outp, int M, int N, int K, int relu, int obf16)
{
    __shared__ ushort As[128 * 64];   // 16 KB
    __shared__ ushort Bs[128 * 64];   // 16 KB

    const int tid = threadIdx.x;
    const int m0 = blockIdx.y * 128, n0 = blockIdx.x * 128;
    const int lane = tid & 63, w = tid >> 6;
    const int wm = (w & 1) * 64, wn = (w >> 1) * 64;
    const int quad = lane >> 4, l16 = lane & 15;

    // staging: wave w, issue j covers rows j*32 + w*8 .. +7 (8 rows x 8 chunks)
    const int rsub = lane >> 3;                       // 0..7 row within group
    const int csrc = (lane & 7) ^ rsub;               // swizzled source chunk
    const int rbase = (w << 3) + rsub;                // w*8 + rsub
    const size_t aRow = (size_t)(m0 + rbase) * K + (size_t)csrc * 8;
    const size_t bRow = (size_t)(n0 + rbase) * K + (size_t)csrc * 8;
    ushort* AsB = As + ((w << 3) << 6);               // (w*8)*64
    ushort* BsB = Bs + ((w << 3) << 6);

    float4v acc[4][4] = {};

    for (int k0 = 0; k0 < K; k0 += 64) {
#pragma unroll
        for (int j = 0; j < 4; ++j)
            async_cp16(A + aRow + k0 + (size_t)(j * 32) * K, AsB + j * 32 * 64);
#pragma unroll
        for (int j = 0; j < 4; ++j)
            async_cp16(Wt + bRow + k0 + (size_t)(j * 32) * K, BsB + j * 32 * 64);
        __syncthreads();   // drains vmcnt -> tiles complete

#pragma unroll
        for (int kk = 0; kk < 2; ++kk) {
            const int offk = (((kk * 4 + quad) ^ (l16 & 7)) << 3);
            short8 af[4], bfr[4];
#pragma unroll
            for (int i = 0; i < 4; ++i) {
                af[i]  = *(const short8*)(As + ((wm + i * 16 + l16) << 6) + offk);
                bfr[i] = *(const short8*)(Bs + ((wn + i * 16 + l16) << 6) + offk);
            }
#pragma unroll
            for (int mi = 0; mi < 4; ++mi)
#pragma unroll
                for (int ni = 0; ni < 4; ++ni)
                    acc[mi][ni] = __builtin_amdgcn_mfma_f32_16x16x32_bf16(
                        af[mi], bfr[ni], acc[mi][ni], 0, 0, 0);
        }
        __syncthreads();
    }

    // epilogue: C/D layout col = lane&15, row = quad*4 + r
    float* outf = (float*)outp;
    ushort* outb = (ushort*)outp;
#pragma unroll
    for (int mi = 0; mi < 4; ++mi) {
#pragma unroll
        for (int ni = 0; ni < 4; ++ni) {
            int col = n0 + wn + ni * 16 + l16;
            if (GUARD && col >= N) continue;
            float bv = bias[col];
            size_t o0 = (size_t)(m0 + wm + mi * 16 + quad * 4) * N + col;
#pragma unroll
            for (int r = 0; r < 4; ++r) {
                float v = acc[mi][ni][r] + bv;
                if (relu) v = fmaxf(v, 0.f);
                size_t o = o0 + (size_t)r * N;
                if (res) v += res[o];
                if (obf16) outb[o] = f2bf(v);
                else       outf[o] = v;
            }
        }
    }
}

// ---------------------------------------------------------------------------
// LayerNorm over last dim (768), fp32 in -> bf16 out. One block per token.
// ---------------------------------------------------------------------------
__global__ __launch_bounds__(256) void ln_kernel(
    const float* __restrict__ X, const float* __restrict__ g,
    const float* __restrict__ b, ushort* __restrict__ O)
{
    const int row = blockIdx.x;
    const int t = threadIdx.x;
    const float* x = X + (size_t)row * D_;
    float v0 = x[t], v1 = x[t + 256], v2 = x[t + 512];
    float s  = v0 + v1 + v2;
    float ss = v0 * v0 + v1 * v1 + v2 * v2;
    block_reduce2(s, ss);
    float mean = s * (1.f / D_);
    float var  = ss * (1.f / D_) - mean * mean;
    float rstd = rsqrtf(var + 1e-5f);
    ushort* o = O + (size_t)row * D_;
    o[t]       = f2bf((v0 - mean) * rstd * g[t]       + b[t]);
    o[t + 256] = f2bf((v1 - mean) * rstd * g[t + 256] + b[t + 256]);
    o[t + 512] = f2bf((v2 - mean) * rstd * g[t + 512] + b[t + 512]);
}

// ---------------------------------------------------------------------------
// Assemble token sequence + embedding LayerNorm -> fp32 residual stream X.
// ---------------------------------------------------------------------------
__global__ __launch_bounds__(256) void assemble_ln_kernel(
    const float* __restrict__ pvec, const float* __restrict__ svec,
    const float* __restrict__ gvec, const int* __restrict__ mask,
    const float* __restrict__ mtok, const float* __restrict__ g,
    const float* __restrict__ b, float* __restrict__ O)
{
    const int row = blockIdx.x;            // b*12 + n
    const int bb = row / N_, n = row % N_;
    const int t = threadIdx.x;
    float v0, v1, v2;
    if (n < NP_) {
        if (mask[bb * NP_ + n]) {
            v0 = mtok[t]; v1 = mtok[t + 256]; v2 = mtok[t + 512];
        } else {
            const float* p = pvec + (size_t)(bb * NP_ + n) * D_;
            v0 = p[t]; v1 = p[t + 256]; v2 = p[t + 512];
        }
    } else if (n == NP_) {
        const float* p = svec + (size_t)bb * D_;
        v0 = p[t]; v1 = p[t + 256]; v2 = p[t + 512];
    } else {
        const float* p = gvec + (size_t)bb * D_;
        v0 = p[t]; v1 = p[t + 256]; v2 = p[t + 512];
    }
    float s  = v0 + v1 + v2;
    float ss = v0 * v0 + v1 * v1 + v2 * v2;
    block_reduce2(s, ss);
    float mean = s * (1.f / D_);
    float var  = ss * (1.f / D_) - mean * mean;
    float rstd = rsqrtf(var + 1e-5f);
    float* o = O + (size_t)row * D_;
    o[t]       = (v0 - mean) * rstd * g[t]       + b[t];
    o[t + 256] = (v1 - mean) * rstd * g[t + 256] + b[t + 256];
    o[t + 512] = (v2 - mean) * rstd * g[t + 512] + b[t + 512];
}

// ---------------------------------------------------------------------------
// Fused attention: one wave per (b, head). bf16 QKV in, bf16 out.
// ---------------------------------------------------------------------------
__global__ __launch_bounds__(64) void attn_kernel(
    const ushort* __restrict__ QKV, ushort* __restrict__ OUT)
{
    const int bh = blockIdx.x;
    const int bb = bh / H_, h = bh % H_;
    const int t = threadIdx.x;

    __shared__ float q[N_][HD_], k[N_][HD_], v[N_][HD_], p[N_][N_];

    const ushort* base = QKV + (size_t)bb * N_ * (3 * D_) + h * HD_;
#pragma unroll
    for (int n = 0; n < N_; ++n) {
        q[n][t] = bf2f(base[n * (3 * D_) + t]);
        k[n][t] = bf2f(base[n * (3 * D_) + D_ + t]);
        v[n][t] = bf2f(base[n * (3 * D_) + 2 * D_ + t]);
    }
    __syncthreads();

    if (t < 32) {
        float freq = exp2f(-(float)t * (13.287712379549449f / 32.0f));
#pragma unroll
        for (int n = 0; n < N_; ++n) {
            float ang = (float)n * freq;
            float sn, cs;
            sincosf(ang, &sn, &cs);
            float xr = q[n][2 * t], xi = q[n][2 * t + 1];
            q[n][2 * t]     = xr * cs - xi * sn;
            q[n][2 * t + 1] = xr * sn + xi * cs;
            xr = k[n][2 * t]; xi = k[n][2 * t + 1];
            k[n][2 * t]     = xr * cs - xi * sn;
            k[n][2 * t + 1] = xr * sn + xi * cs;
        }
    }
    __syncthreads();

    for (int idx = t; idx < N_ * N_; idx += 64) {
        int i = idx / N_, j = idx % N_;
        float s = 0.f;
#pragma unroll
        for (int d = 0; d < HD_; ++d) s += q[i][d] * k[j][d];
        p[i][j] = s * 0.125f;
    }
    __syncthreads();

    if (t < N_) {
        float mx = -1e30f;
#pragma unroll
        for (int j = 0; j < N_; ++j) mx = fmaxf(mx, p[t][j]);
        float e[N_], sum = 0.f;
#pragma unroll
        for (int j = 0; j < N_; ++j) { e[j] = expf(p[t][j] - mx); sum += e[j]; }
        float inv = 1.f / sum;
#pragma unroll
        for (int j = 0; j < N_; ++j) p[t][j] = e[j] * inv;
    }
    __syncthreads();

#pragma unroll
    for (int i = 0; i < N_; ++i) {
        float o = 0.f;
#pragma unroll
        for (int j = 0; j < N_; ++j) o += p[i][j] * v[j][t];
        OUT[((size_t)bb * N_ + i) * D_ + h * HD_ + t] = f2bf(o);
    }
}

// ---------------------------------------------------------------------------
// Token-select + bf16 convert: X[B,12,D] fp32 -> XS[B*10, D] bf16.
// ---------------------------------------------------------------------------
__global__ __launch_bounds__(256) void tokensel_kernel(
    const float* __restrict__ X, ushort* __restrict__ XS)
{
    const int r = blockIdx.x;
    const int c = blockIdx.y * 256 + threadIdx.x;
    XS[(size_t)r * D_ + c] =
        f2bf(X[(size_t)((r / 10) * 12 + (r % 10)) * D_ + c]);
}

// ---------------------------------------------------------------------------
// Loss
// ---------------------------------------------------------------------------
__global__ __launch_bounds__(256) void loss_partial_kernel(
    const float* __restrict__ pred, const float* __restrict__ patches,
    const int* __restrict__ mask, float* __restrict__ part)
{
    const int row = blockIdx.x;
    const int t = threadIdx.x;
    if (!mask[row]) {
        if (t == 0) part[row] = 0.f;
        return;
    }
    const int bb = row / NP_, n = row % NP_;
    float s = 0.f;
    for (int kk = t; kk < C_ * PL_; kk += 256) {
        int c = kk / PL_, pp = kk % PL_;
        float tgt = patches[((size_t)(bb * C_ + c) * NP_ + n) * PL_ + pp];
        float d = pred[(size_t)row * (C_ * PL_) + kk] - tgt;
        s += d * d;
    }
    float dummy = 0.f;
    block_reduce2(s, dummy);
    if (t == 0) part[row] = s;
}

__global__ __launch_bounds__(256) void loss_final_kernel(
    const float* __restrict__ part, const int* __restrict__ mask,
    float* __restrict__ out)
{
    const int t = threadIdx.x;
    float s = 0.f, cnt = 0.f;
    for (int i = t; i < B_ * NP_; i += 256) {
        s += part[i];
        cnt += (float)mask[i];
    }
    block_reduce2(s, cnt);
    if (t == 0) out[0] = s / (cnt * (float)(C_ * PL_));
}

// ---------------------------------------------------------------------------
// Host launch
// ---------------------------------------------------------------------------
extern "C" void kernel_launch(void* const* d_in, const int* in_sizes, int n_in,
                              void* d_out, int out_size, void* d_ws, size_t ws_size,
                              hipStream_t stream) {
    const float* patches = (const float*)d_in[0];
    const float* stats   = (const float*)d_in[1];
    const float* topo    = (const float*)d_in[2];
    const int*   mask    = (const int*)d_in[3];
    const float* patch_w = (const float*)d_in[4];
    const float* patch_b = (const float*)d_in[5];
    const float* stat_w  = (const float*)d_in[6];
    const float* stat_b  = (const float*)d_in[7];
    const float* topo_w  = (const float*)d_in[8];
    const float* topo_b  = (const float*)d_in[9];
    const float* mtok    = (const float*)d_in[10];
    const float* emb_g   = (const float*)d_in[11];
    const float* emb_b   = (const float*)d_in[12];
    const float* ln1_g   = (const float*)d_in[13];
    const float* ln1_b   = (const float*)d_in[14];
    const float* qkv_w   = (const float*)d_in[15];
    const float* qkv_b   = (const float*)d_in[16];
    const float* proj_w  = (const float*)d_in[17];
    const float* proj_b  = (const float*)d_in[18];
    const float* ln2_g   = (const float*)d_in[19];
    const float* ln2_b   = (const float*)d_in[20];
    const float* f1_w    = (const float*)d_in[21];
    const float* f1_b    = (const float*)d_in[22];
    const float* f2_w    = (const float*)d_in[23];
    const float* f2_b    = (const float*)d_in[24];
    const float* h1_w    = (const float*)d_in[25];
    const float* h1_b    = (const float*)d_in[26];
    const float* h2_w    = (const float*)d_in[27];
    const float* h2_b    = (const float*)d_in[28];

    // ---- workspace layout (~229 MB) ----
    const size_t XSZ = (size_t)B_ * N_ * D_;              // 9,437,184
    float*  X    = (float*)d_ws;                          // fp32 residual
    ushort* HB   = (ushort*)(X + XSZ);                    // bf16 LN/attn buf
    ushort* BIGS = HB + XSZ;                              // 28,311,552 shorts
    float*  PART = (float*)(BIGS + (size_t)B_ * N_ * 3 * D_);
    ushort* WB   = (ushort*)(PART + (size_t)B_ * NP_);

    // bf16 transposed weights
    ushort* qkvT  = WB;
    ushort* projT = qkvT + (size_t)L_ * 3 * D_ * D_;
    ushort* f1T   = projT + (size_t)L_ * D_ * D_;
    ushort* f2T   = f1T + (size_t)L_ * 2 * D_ * D_;
    ushort* h1T   = f2T + (size_t)L_ * 2 * D_ * D_;
    ushort* h2T   = h1T + (size_t)D_ * D_;                // [384, 768] padded
    ushort* pwT   = h2T + (size_t)384 * D_;               // [768, 320] padded

    // BIGS region reuse (lifetimes disjoint):
    ushort* QKV  = BIGS;                                  // [12288,2304] bf16
    float*  PVEC = (float*)BIGS;                          // [10240,768] fp32
    float*  SVEC = PVEC + (size_t)B_ * NP_ * D_;
    float*  GVEC = SVEC + (size_t)B_ * D_;
    ushort* PB   = (ushort*)(GVEC + (size_t)B_ * D_);     // [10240,320] bf16
    ushort* MID  = BIGS;                                  // [12288,1536] bf16
    float*  PRED = (float*)BIGS;                          // [10240,300] fp32
    ushort* XS   = BIGS + (size_t)2 * B_ * NP_ * 300;     // [10240,768] bf16
    ushort* PMID = XS + (size_t)B_ * NP_ * D_;            // [10240,768] bf16

    const dim3 blk(256);

    // ---- weight convert+transpose (batched over layers) ----
    transpose_bf16_b<<<dim3(72, 24, L_), blk, 0, stream>>>(
        qkv_w, qkvT, D_, 3 * D_, D_, 3 * D_, (size_t)D_ * 3 * D_, (size_t)3 * D_ * D_);
    transpose_bf16_b<<<dim3(24, 24, L_), blk, 0, stream>>>(
        proj_w, projT, D_, D_, D_, D_, (size_t)D_ * D_, (size_t)D_ * D_);
    transpose_bf16_b<<<dim3(48, 24, L_), blk, 0, stream>>>(
        f1_w, f1T, D_, 2 * D_, D_, 2 * D_, (size_t)D_ * 2 * D_, (size_t)2 * D_ * D_);
    transpose_bf16_b<<<dim3(24, 48, L_), blk, 0, stream>>>(
        f2_w, f2T, 2 * D_, D_, 2 * D_, D_, (size_t)2 * D_ * D_, (size_t)2 * D_ * D_);
    transpose_bf16_b<<<dim3(24, 24, 1), blk, 0, stream>>>(
        h1_w, h1T, D_, D_, D_, D_, 0, 0);
    transpose_bf16_b<<<dim3(12, 24, 1), blk, 0, stream>>>(
        h2_w, h2T, D_, 300, D_, 384, 0, 0);               // pad N to 384
    transpose_bf16_b<<<dim3(24, 10, 1), blk, 0, stream>>>(
        patch_w, pwT, 300, D_, 320, D_, 0, 0);            // pad K to 320

    // ---- embed ----
    patch_gather<<<(B_ * NP_ * 320) / 256, blk, 0, stream>>>(patches, PB);
    mfma_gemm<false><<<dim3(6, 80), blk, 0, stream>>>(
        PB, pwT, patch_b, nullptr, PVEC, B_ * NP_, D_, 320, 0, 0);
    gemm_kernel<<<dim3(D_ / 64, B_ / 64), blk, 0, stream>>>(
        stats, stat_w, stat_b, SVEC, B_, D_, 56);
    gemm_kernel<<<dim3(D_ / 64, B_ / 64), blk, 0, stream>>>(
        topo, topo_w, topo_b, GVEC, B_, D_, 24);
    assemble_ln_kernel<<<B_ * N_, blk, 0, stream>>>(
        PVEC, SVEC, GVEC, mask, mtok, emb_g, emb_b, X);

    // ---- transformer layers ----
    for (int l = 0; l < L_; ++l) {
        ln_kernel<<<B_ * N_, blk, 0, stream>>>(X, ln1_g + l * D_, ln1_b + l * D_, HB);
        mfma_gemm<false><<<dim3(18, 96), blk, 0, stream>>>(
            HB, qkvT + (size_t)l * 3 * D_ * D_, qkv_b + l * 3 * D_, nullptr, QKV,
            B_ * N_, 3 * D_, D_, 0, 1);
        attn_kernel<<<B_ * H_, dim3(64), 0, stream>>>(QKV, HB);
        mfma_gemm<false><<<dim3(6, 96), blk, 0, stream>>>(
            HB, projT + (size_t)l * D_ * D_, proj_b + l * D_, X, X,
            B_ * N_, D_, D_, 0, 0);
        ln_kernel<<<B_ * N_, blk, 0, stream>>>(X, ln2_g + l * D_, ln2_b + l * D_, HB);
        mfma_gemm<false><<<dim3(12, 96), blk, 0, stream>>>(
            HB, f1T + (size_t)l * 2 * D_ * D_, f1_b + l * 2 * D_, nullptr, MID,
            B_ * N_, 2 * D_, D_, 1, 1);
        mfma_gemm<false><<<dim3(6, 96), blk, 0, stream>>>(
            MID, f2T + (size_t)l * 2 * D_ * D_, f2_b + l * D_, X, X,
            B_ * N_, D_, 2 * D_, 0, 0);
    }

    // ---- head + loss ----
    tokensel_kernel<<<dim3(B_ * NP_, 3), blk, 0, stream>>>(X, XS);
    mfma_gemm<false><<<dim3(6, 80), blk, 0, stream>>>(
        XS, h1T, h1_b, nullptr, PMID, B_ * NP_, D_, D_, 1, 1);
    mfma_gemm<true><<<dim3(3, 80), blk, 0, stream>>>(
        PMID, h2T, h2_b, nullptr, PRED, B_ * NP_, C_ * PL_, D_, 0, 0);
    loss_partial_kernel<<<B_ * NP_, blk, 0, stream>>>(PRED, patches, mask, PART);
    loss_final_kernel<<<1, blk, 0, stream>>>(PART, mask, (float*)d_out);
}

// Round 6
// 4486.033 us; speedup vs baseline: 1.1439x; 1.1439x over previous
//
#include <hip/hip_runtime.h>
#include <hip/hip_bf16.h>
#include <cstddef>

// Problem constants
#define B_   1024
#define C_   3
#define NP_  10
#define PL_  100
#define D_   768
#define H_   12
#define L_   12
#define N_   12   // NP + 2
#define HD_  64

typedef __attribute__((ext_vector_type(8))) short short8;   // 8 x bf16 (4 VGPRs)
typedef __attribute__((ext_vector_type(4))) float float4v;  // 4 x f32 acc

__device__ __forceinline__ ushort f2bf(float x) {
    __hip_bfloat16 h = __float2bfloat16(x);
    return *(ushort*)&h;
}
__device__ __forceinline__ float bf2f(ushort u) {
    union { unsigned u32; float f; } x; x.u32 = ((unsigned)u) << 16; return x.f;
}

// async global->LDS 16B copy: per-lane global addr, wave-uniform LDS base,
// HW writes lane i at base + i*16.
__device__ __forceinline__ void async_cp16(const ushort* g, ushort* lds) {
    __builtin_amdgcn_global_load_lds(
        (const __attribute__((address_space(1))) unsigned int*)g,
        (__attribute__((address_space(3))) unsigned int*)lds, 16, 0, 0);
}

// ---------------------------------------------------------------------------
// Block-wide reduction of two floats across 256 threads (4 waves of 64).
// ---------------------------------------------------------------------------
__device__ __forceinline__ void block_reduce2(float& a, float& b) {
    __shared__ float sa[4], sb[4];
#pragma unroll
    for (int off = 32; off > 0; off >>= 1) {
        a += __shfl_down(a, off);
        b += __shfl_down(b, off);
    }
    int wid = threadIdx.x >> 6, lane = threadIdx.x & 63;
    __syncthreads();
    if (lane == 0) { sa[wid] = a; sb[wid] = b; }
    __syncthreads();
    if (threadIdx.x == 0) {
        float ta = 0.f, tb = 0.f;
#pragma unroll
        for (int i = 0; i < 4; ++i) { ta += sa[i]; tb += sb[i]; }
        sa[0] = ta; sb[0] = tb;
    }
    __syncthreads();
    a = sa[0]; b = sb[0];
}

// ---------------------------------------------------------------------------
// fp32 tiled GEMM — only for the tiny stats/topo embeds (K=56/24).
// ---------------------------------------------------------------------------
#define BM 64
#define BN 64
#define BK 16

__global__ __launch_bounds__(256) void gemm_kernel(
    const float* __restrict__ A, const float* __restrict__ W,
    const float* __restrict__ bias, float* __restrict__ C,
    int M, int N, int K)
{
    __shared__ float As[BK][BM];
    __shared__ float Ws[BK][BN];

    const int tid = threadIdx.x;
    const int tx = tid & 15, ty = tid >> 4;
    const int m0 = blockIdx.y * BM, n0 = blockIdx.x * BN;

    float acc[4][4] = {};

    const int am  = tid & 63;
    const int akq = tid >> 6;
    const int wn  = (tid & 15) * 4;
    const int wk  = tid >> 4;

    for (int k0 = 0; k0 < K; k0 += BK) {
        float4 av = make_float4(0.f, 0.f, 0.f, 0.f);
        int gm = m0 + am;
        int gk = k0 + akq * 4;
        if (gm < M && gk + 3 < K)
            av = *(const float4*)(A + (size_t)gm * K + gk);
        else if (gm < M) {
            float tmp[4] = {0.f, 0.f, 0.f, 0.f};
            for (int i = 0; i < 4; ++i)
                if (gk + i < K) tmp[i] = A[(size_t)gm * K + gk + i];
            av = make_float4(tmp[0], tmp[1], tmp[2], tmp[3]);
        }
        As[akq * 4 + 0][am] = av.x;
        As[akq * 4 + 1][am] = av.y;
        As[akq * 4 + 2][am] = av.z;
        As[akq * 4 + 3][am] = av.w;

        float4 wv = make_float4(0.f, 0.f, 0.f, 0.f);
        int gkw = k0 + wk, gn = n0 + wn;
        if (gkw < K && gn < N)
            wv = *(const float4*)(W + (size_t)gkw * N + gn);
        *(float4*)&Ws[wk][wn] = wv;

        __syncthreads();

#pragma unroll
        for (int kk = 0; kk < BK; ++kk) {
            float4 a = *(const float4*)&As[kk][ty * 4];
            float4 b = *(const float4*)&Ws[kk][tx * 4];
            acc[0][0] += a.x * b.x; acc[0][1] += a.x * b.y; acc[0][2] += a.x * b.z; acc[0][3] += a.x * b.w;
            acc[1][0] += a.y * b.x; acc[1][1] += a.y * b.y; acc[1][2] += a.y * b.z; acc[1][3] += a.y * b.w;
            acc[2][0] += a.z * b.x; acc[2][1] += a.z * b.y; acc[2][2] += a.z * b.z; acc[2][3] += a.z * b.w;
            acc[3][0] += a.w * b.x; acc[3][1] += a.w * b.y; acc[3][2] += a.w * b.z; acc[3][3] += a.w * b.w;
        }
        __syncthreads();
    }

#pragma unroll
    for (int i = 0; i < 4; ++i) {
        int row = m0 + ty * 4 + i;
        if (row >= M) continue;
#pragma unroll
        for (int j = 0; j < 4; ++j) {
            int col = n0 + tx * 4 + j;
            if (col >= N) continue;
            C[(size_t)row * N + col] = acc[i][j] + bias[col];
        }
    }
}

// ---------------------------------------------------------------------------
// Batched weight convert+transpose: fp32 [K,N] -> bf16 [Npad, Kpad]
// (zero-filled in [N,Npad) rows and [K,Kpad) cols). blockIdx.z = batch.
// ---------------------------------------------------------------------------
__global__ __launch_bounds__(256) void transpose_bf16_b(
    const float* __restrict__ in, ushort* __restrict__ out,
    int K, int N, int Kpad, int Npad, size_t in_stride, size_t out_stride)
{
    __shared__ float t[32][33];
    const float* inz = in + (size_t)blockIdx.z * in_stride;
    ushort* outz = out + (size_t)blockIdx.z * out_stride;
    const int tx = threadIdx.x & 31, ty = threadIdx.x >> 5;  // 32 x 8
    const int k0 = blockIdx.y * 32, n0 = blockIdx.x * 32;
#pragma unroll
    for (int i = 0; i < 4; ++i) {
        int k = k0 + ty + i * 8, n = n0 + tx;
        t[ty + i * 8][tx] = (k < K && n < N) ? inz[(size_t)k * N + n] : 0.f;
    }
    __syncthreads();
#pragma unroll
    for (int i = 0; i < 4; ++i) {
        int n = n0 + ty + i * 8, k = k0 + tx;
        if (n < Npad && k < Kpad)
            outz[(size_t)n * Kpad + k] = f2bf(t[tx][ty + i * 8]);
    }
}

// ---------------------------------------------------------------------------
// Patch gather -> bf16 A matrix [B*NP, 320] (zero-padded cols 300..319).
// ---------------------------------------------------------------------------
__global__ __launch_bounds__(256) void patch_gather(
    const float* __restrict__ patches, ushort* __restrict__ PB)
{
    int idx = blockIdx.x * 256 + threadIdx.x;   // B*NP*320
    int row = idx / 320, col = idx % 320;
    ushort v = 0;
    if (col < 300) {
        int bb = row / 10, n = row % 10, c = col / 100, p = col % 100;
        v = f2bf(patches[(size_t)((bb * 3 + c) * 10 + n) * 100 + p]);
    }
    PB[idx] = v;
}

// ---------------------------------------------------------------------------
// bf16 MFMA GEMM: out[M,N] = A[M,K] @ Wt[Npad,K]^T + bias (+res)
// 128x128 tile, BK=32 (16 KB LDS -> R4 occupancy), global_load_lds width=16
// staging, XOR chunk swizzle: 16B chunk c of row r lives at LDS chunk
// c ^ ((r>>1)&3). Octet-model conflict-free ds_read_b128 (each 8-lane group
// covers all 8 bank-frames). M % 128 == 0, K % 32 == 0, Wt zero-padded to
// >= gridDim.x*128 rows. GUARD: store-guard col < N (h2 only).
// ---------------------------------------------------------------------------
template<bool GUARD>
__global__ __launch_bounds__(256) void mfma_gemm(
    const ushort* __restrict__ A, const ushort* __restrict__ Wt,
    const float* __restrict__ bias, const float* __restrict__ res,
    void* __restrict__ outp, int M, int N, int K, int relu, int obf16)
{
    __shared__ ushort As[128 * 32];   // 8 KB
    __shared__ ushort Bs[128 * 32];   // 8 KB

    const int tid = threadIdx.x;
    const int m0 = blockIdx.y * 128, n0 = blockIdx.x * 128;
    const int lane = tid & 63, w = tid >> 6;
    const int wm = (w & 1) * 64, wn = (w >> 1) * 64;
    const int quad = lane >> 4, l16 = lane & 15;

    // staging: wave issue = 16 rows x 4 chunks (64 lanes x 16B).
    // lane -> row lane>>2, LDS chunk lane&3; source chunk XOR-swizzled.
    const int r_sub = lane >> 2, c_lds = lane & 3;
    const int rloc = (w << 4) + r_sub;               // 0..63 (issue0; +64 issue1)
    const int csrc = c_lds ^ ((rloc >> 1) & 3);      // same for rloc+64
    const size_t aoff0 = (size_t)(m0 + rloc) * K + csrc * 8;
    const size_t aoff1 = aoff0 + (size_t)64 * K;
    const size_t boff0 = (size_t)(n0 + rloc) * K + csrc * 8;
    const size_t boff1 = boff0 + (size_t)64 * K;
    ushort* AsW0 = As + (w << 9);                    // rows w*16..+15
    ushort* AsW1 = As + 2048 + (w << 9);             // rows 64+w*16..+15
    ushort* BsW0 = Bs + (w << 9);
    ushort* BsW1 = Bs + 2048 + (w << 9);

    // fragment read chunk (swizzle inverse); independent of subtile index
    const int roff = (quad ^ ((l16 >> 1) & 3)) << 3; // shorts

    float4v acc[4][4] = {};

    for (int k0 = 0; k0 < K; k0 += 32) {
        async_cp16(A + aoff0 + k0, AsW0);
        async_cp16(A + aoff1 + k0, AsW1);
        async_cp16(Wt + boff0 + k0, BsW0);
        async_cp16(Wt + boff1 + k0, BsW1);
        __syncthreads();   // drains vmcnt -> tiles complete

        short8 af[4], bfr[4];
#pragma unroll
        for (int i = 0; i < 4; ++i) {
            af[i]  = *(const short8*)(As + ((wm + i * 16 + l16) << 5) + roff);
            bfr[i] = *(const short8*)(Bs + ((wn + i * 16 + l16) << 5) + roff);
        }
#pragma unroll
        for (int mi = 0; mi < 4; ++mi)
#pragma unroll
            for (int ni = 0; ni < 4; ++ni)
                acc[mi][ni] = __builtin_amdgcn_mfma_f32_16x16x32_bf16(
                    af[mi], bfr[ni], acc[mi][ni], 0, 0, 0);
        __syncthreads();
    }

    // epilogue: C/D layout col = lane&15, row = quad*4 + r
    float* outf = (float*)outp;
    ushort* outb = (ushort*)outp;
#pragma unroll
    for (int mi = 0; mi < 4; ++mi) {
#pragma unroll
        for (int ni = 0; ni < 4; ++ni) {
            int col = n0 + wn + ni * 16 + l16;
            if (GUARD && col >= N) continue;
            float bv = bias[col];
            size_t o0 = (size_t)(m0 + wm + mi * 16 + quad * 4) * N + col;
#pragma unroll
            for (int r = 0; r < 4; ++r) {
                float v = acc[mi][ni][r] + bv;
                if (relu) v = fmaxf(v, 0.f);
                size_t o = o0 + (size_t)r * N;
                if (res) v += res[o];
                if (obf16) outb[o] = f2bf(v);
                else       outf[o] = v;
            }
        }
    }
}

// ---------------------------------------------------------------------------
// LayerNorm over last dim (768), fp32 in -> bf16 out. One block per token.
// ---------------------------------------------------------------------------
__global__ __launch_bounds__(256) void ln_kernel(
    const float* __restrict__ X, const float* __restrict__ g,
    const float* __restrict__ b, ushort* __restrict__ O)
{
    const int row = blockIdx.x;
    const int t = threadIdx.x;
    const float* x = X + (size_t)row * D_;
    float v0 = x[t], v1 = x[t + 256], v2 = x[t + 512];
    float s  = v0 + v1 + v2;
    float ss = v0 * v0 + v1 * v1 + v2 * v2;
    block_reduce2(s, ss);
    float mean = s * (1.f / D_);
    float var  = ss * (1.f / D_) - mean * mean;
    float rstd = rsqrtf(var + 1e-5f);
    ushort* o = O + (size_t)row * D_;
    o[t]       = f2bf((v0 - mean) * rstd * g[t]       + b[t]);
    o[t + 256] = f2bf((v1 - mean) * rstd * g[t + 256] + b[t + 256]);
    o[t + 512] = f2bf((v2 - mean) * rstd * g[t + 512] + b[t + 512]);
}

// ---------------------------------------------------------------------------
// Assemble token sequence + embedding LayerNorm -> fp32 residual stream X.
// ---------------------------------------------------------------------------
__global__ __launch_bounds__(256) void assemble_ln_kernel(
    const float* __restrict__ pvec, const float* __restrict__ svec,
    const float* __restrict__ gvec, const int* __restrict__ mask,
    const float* __restrict__ mtok, const float* __restrict__ g,
    const float* __restrict__ b, float* __restrict__ O)
{
    const int row = blockIdx.x;            // b*12 + n
    const int bb = row / N_, n = row % N_;
    const int t = threadIdx.x;
    float v0, v1, v2;
    if (n < NP_) {
        if (mask[bb * NP_ + n]) {
            v0 = mtok[t]; v1 = mtok[t + 256]; v2 = mtok[t + 512];
        } else {
            const float* p = pvec + (size_t)(bb * NP_ + n) * D_;
            v0 = p[t]; v1 = p[t + 256]; v2 = p[t + 512];
        }
    } else if (n == NP_) {
        const float* p = svec + (size_t)bb * D_;
        v0 = p[t]; v1 = p[t + 256]; v2 = p[t + 512];
    } else {
        const float* p = gvec + (size_t)bb * D_;
        v0 = p[t]; v1 = p[t + 256]; v2 = p[t + 512];
    }
    float s  = v0 + v1 + v2;
    float ss = v0 * v0 + v1 * v1 + v2 * v2;
    block_reduce2(s, ss);
    float mean = s * (1.f / D_);
    float var  = ss * (1.f / D_) - mean * mean;
    float rstd = rsqrtf(var + 1e-5f);
    float* o = O + (size_t)row * D_;
    o[t]       = (v0 - mean) * rstd * g[t]       + b[t];
    o[t + 256] = (v1 - mean) * rstd * g[t + 256] + b[t + 256];
    o[t + 512] = (v2 - mean) * rstd * g[t + 512] + b[t + 512];
}

// ---------------------------------------------------------------------------
// Fused attention: one wave per (b, head). bf16 QKV in, bf16 out.
// ---------------------------------------------------------------------------
__global__ __launch_bounds__(64) void attn_kernel(
    const ushort* __restrict__ QKV, ushort* __restrict__ OUT)
{
    const int bh = blockIdx.x;
    const int bb = bh / H_, h = bh % H_;
    const int t = threadIdx.x;

    __shared__ float q[N_][HD_], k[N_][HD_], v[N_][HD_], p[N_][N_];

    const ushort* base = QKV + (size_t)bb * N_ * (3 * D_) + h * HD_;
#pragma unroll
    for (int n = 0; n < N_; ++n) {
        q[n][t] = bf2f(base[n * (3 * D_) + t]);
        k[n][t] = bf2f(base[n * (3 * D_) + D_ + t]);
        v[n][t] = bf2f(base[n * (3 * D_) + 2 * D_ + t]);
    }
    __syncthreads();

    if (t < 32) {
        float freq = exp2f(-(float)t * (13.287712379549449f / 32.0f));
#pragma unroll
        for (int n = 0; n < N_; ++n) {
            float ang = (float)n * freq;
            float sn, cs;
            sincosf(ang, &sn, &cs);
            float xr = q[n][2 * t], xi = q[n][2 * t + 1];
            q[n][2 * t]     = xr * cs - xi * sn;
            q[n][2 * t + 1] = xr * sn + xi * cs;
            xr = k[n][2 * t]; xi = k[n][2 * t + 1];
            k[n][2 * t]     = xr * cs - xi * sn;
            k[n][2 * t + 1] = xr * sn + xi * cs;
        }
    }
    __syncthreads();

    for (int idx = t; idx < N_ * N_; idx += 64) {
        int i = idx / N_, j = idx % N_;
        float s = 0.f;
#pragma unroll
        for (int d = 0; d < HD_; ++d) s += q[i][d] * k[j][d];
        p[i][j] = s * 0.125f;
    }
    __syncthreads();

    if (t < N_) {
        float mx = -1e30f;
#pragma unroll
        for (int j = 0; j < N_; ++j) mx = fmaxf(mx, p[t][j]);
        float e[N_], sum = 0.f;
#pragma unroll
        for (int j = 0; j < N_; ++j) { e[j] = expf(p[t][j] - mx); sum += e[j]; }
        float inv = 1.f / sum;
#pragma unroll
        for (int j = 0; j < N_; ++j) p[t][j] = e[j] * inv;
    }
    __syncthreads();

#pragma unroll
    for (int i = 0; i < N_; ++i) {
        float o = 0.f;
#pragma unroll
        for (int j = 0; j < N_; ++j) o += p[i][j] * v[j][t];
        OUT[((size_t)bb * N_ + i) * D_ + h * HD_ + t] = f2bf(o);
    }
}

// ---------------------------------------------------------------------------
// Token-select + bf16 convert: X[B,12,D] fp32 -> XS[B*10, D] bf16.
// ---------------------------------------------------------------------------
__global__ __launch_bounds__(256) void tokensel_kernel(
    const float* __restrict__ X, ushort* __restrict__ XS)
{
    const int r = blockIdx.x;
    const int c = blockIdx.y * 256 + threadIdx.x;
    XS[(size_t)r * D_ + c] =
        f2bf(X[(size_t)((r / 10) * 12 + (r % 10)) * D_ + c]);
}

// ---------------------------------------------------------------------------
// Loss
// ---------------------------------------------------------------------------
__global__ __launch_bounds__(256) void loss_partial_kernel(
    const float* __restrict__ pred, const float* __restrict__ patches,
    const int* __restrict__ mask, float* __restrict__ part)
{
    const int row = blockIdx.x;
    const int t = threadIdx.x;
    if (!mask[row]) {
        if (t == 0) part[row] = 0.f;
        return;
    }
    const int bb = row / NP_, n = row % NP_;
    float s = 0.f;
    for (int kk = t; kk < C_ * PL_; kk += 256) {
        int c = kk / PL_, pp = kk % PL_;
        float tgt = patches[((size_t)(bb * C_ + c) * NP_ + n) * PL_ + pp];
        float d = pred[(size_t)row * (C_ * PL_) + kk] - tgt;
        s += d * d;
    }
    float dummy = 0.f;
    block_reduce2(s, dummy);
    if (t == 0) part[row] = s;
}

__global__ __launch_bounds__(256) void loss_final_kernel(
    const float* __restrict__ part, const int* __restrict__ mask,
    float* __restrict__ out)
{
    const int t = threadIdx.x;
    float s = 0.f, cnt = 0.f;
    for (int i = t; i < B_ * NP_; i += 256) {
        s += part[i];
        cnt += (float)mask[i];
    }
    block_reduce2(s, cnt);
    if (t == 0) out[0] = s / (cnt * (float)(C_ * PL_));
}

// ---------------------------------------------------------------------------
// Host launch
// ---------------------------------------------------------------------------
extern "C" void kernel_launch(void* const* d_in, const int* in_sizes, int n_in,
                              void* d_out, int out_size, void* d_ws, size_t ws_size,
                              hipStream_t stream) {
    const float* patches = (const float*)d_in[0];
    const float* stats   = (const float*)d_in[1];
    const float* topo    = (const float*)d_in[2];
    const int*   mask    = (const int*)d_in[3];
    const float* patch_w = (const float*)d_in[4];
    const float* patch_b = (const float*)d_in[5];
    const float* stat_w  = (const float*)d_in[6];
    const float* stat_b  = (const float*)d_in[7];
    const float* topo_w  = (const float*)d_in[8];
    const float* topo_b  = (const float*)d_in[9];
    const float* mtok    = (const float*)d_in[10];
    const float* emb_g   = (const float*)d_in[11];
    const float* emb_b   = (const float*)d_in[12];
    const float* ln1_g   = (const float*)d_in[13];
    const float* ln1_b   = (const float*)d_in[14];
    const float* qkv_w   = (const float*)d_in[15];
    const float* qkv_b   = (const float*)d_in[16];
    const float* proj_w  = (const float*)d_in[17];
    const float* proj_b  = (const float*)d_in[18];
    const float* ln2_g   = (const float*)d_in[19];
    const float* ln2_b   = (const float*)d_in[20];
    const float* f1_w    = (const float*)d_in[21];
    const float* f1_b    = (const float*)d_in[22];
    const float* f2_w    = (const float*)d_in[23];
    const float* f2_b    = (const float*)d_in[24];
    const float* h1_w    = (const float*)d_in[25];
    const float* h1_b    = (const float*)d_in[26];
    const float* h2_w    = (const float*)d_in[27];
    const float* h2_b    = (const float*)d_in[28];

    // ---- workspace layout (~229 MB) ----
    const size_t XSZ = (size_t)B_ * N_ * D_;              // 9,437,184
    float*  X    = (float*)d_ws;                          // fp32 residual
    ushort* HB   = (ushort*)(X + XSZ);                    // bf16 LN/attn buf
    ushort* BIGS = HB + XSZ;                              // 28,311,552 shorts
    float*  PART = (float*)(BIGS + (size_t)B_ * N_ * 3 * D_);
    ushort* WB   = (ushort*)(PART + (size_t)B_ * NP_);

    // bf16 transposed weights
    ushort* qkvT  = WB;
    ushort* projT = qkvT + (size_t)L_ * 3 * D_ * D_;
    ushort* f1T   = projT + (size_t)L_ * D_ * D_;
    ushort* f2T   = f1T + (size_t)L_ * 2 * D_ * D_;
    ushort* h1T   = f2T + (size_t)L_ * 2 * D_ * D_;
    ushort* h2T   = h1T + (size_t)D_ * D_;                // [384, 768] padded
    ushort* pwT   = h2T + (size_t)384 * D_;               // [768, 320] padded

    // BIGS region reuse (lifetimes disjoint):
    ushort* QKV  = BIGS;                                  // [12288,2304] bf16
    float*  PVEC = (float*)BIGS;                          // [10240,768] fp32
    float*  SVEC = PVEC + (size_t)B_ * NP_ * D_;
    float*  GVEC = SVEC + (size_t)B_ * D_;
    ushort* PB   = (ushort*)(GVEC + (size_t)B_ * D_);     // [10240,320] bf16
    ushort* MID  = BIGS;                                  // [12288,1536] bf16
    float*  PRED = (float*)BIGS;                          // [10240,300] fp32
    ushort* XS   = BIGS + (size_t)2 * B_ * NP_ * 300;     // [10240,768] bf16
    ushort* PMID = XS + (size_t)B_ * NP_ * D_;            // [10240,768] bf16

    const dim3 blk(256);

    // ---- weight convert+transpose (batched over layers) ----
    transpose_bf16_b<<<dim3(72, 24, L_), blk, 0, stream>>>(
        qkv_w, qkvT, D_, 3 * D_, D_, 3 * D_, (size_t)D_ * 3 * D_, (size_t)3 * D_ * D_);
    transpose_bf16_b<<<dim3(24, 24, L_), blk, 0, stream>>>(
        proj_w, projT, D_, D_, D_, D_, (size_t)D_ * D_, (size_t)D_ * D_);
    transpose_bf16_b<<<dim3(48, 24, L_), blk, 0, stream>>>(
        f1_w, f1T, D_, 2 * D_, D_, 2 * D_, (size_t)D_ * 2 * D_, (size_t)2 * D_ * D_);
    transpose_bf16_b<<<dim3(24, 48, L_), blk, 0, stream>>>(
        f2_w, f2T, 2 * D_, D_, 2 * D_, D_, (size_t)2 * D_ * D_, (size_t)2 * D_ * D_);
    transpose_bf16_b<<<dim3(24, 24, 1), blk, 0, stream>>>(
        h1_w, h1T, D_, D_, D_, D_, 0, 0);
    transpose_bf16_b<<<dim3(12, 24, 1), blk, 0, stream>>>(
        h2_w, h2T, D_, 300, D_, 384, 0, 0);               // pad N to 384
    transpose_bf16_b<<<dim3(24, 10, 1), blk, 0, stream>>>(
        patch_w, pwT, 300, D_, 320, D_, 0, 0);            // pad K to 320

    // ---- embed ----
    patch_gather<<<(B_ * NP_ * 320) / 256, blk, 0, stream>>>(patches, PB);
    mfma_gemm<false><<<dim3(6, 80), blk, 0, stream>>>(
        PB, pwT, patch_b, nullptr, PVEC, B_ * NP_, D_, 320, 0, 0);
    gemm_kernel<<<dim3(D_ / 64, B_ / 64), blk, 0, stream>>>(
        stats, stat_w, stat_b, SVEC, B_, D_, 56);
    gemm_kernel<<<dim3(D_ / 64, B_ / 64), blk, 0, stream>>>(
        topo, topo_w, topo_b, GVEC, B_, D_, 24);
    assemble_ln_kernel<<<B_ * N_, blk, 0, stream>>>(
        PVEC, SVEC, GVEC, mask, mtok, emb_g, emb_b, X);

    // ---- transformer layers ----
    for (int l = 0; l < L_; ++l) {
        ln_kernel<<<B_ * N_, blk, 0, stream>>>(X, ln1_g + l * D_, ln1_b + l * D_, HB);
        mfma_gemm<false><<<dim3(18, 96), blk, 0, stream>>>(
            HB, qkvT + (size_t)l * 3 * D_ * D_, qkv_b + l * 3 * D_, nullptr, QKV,
            B_ * N_, 3 * D_, D_, 0, 1);
        attn_kernel<<<B_ * H_, dim3(64), 0, stream>>>(QKV, HB);
        mfma_gemm<false><<<dim3(6, 96), blk, 0, stream>>>(
            HB, projT + (size_t)l * D_ * D_, proj_b + l * D_, X, X,
            B_ * N_, D_, D_, 0, 0);
        ln_kernel<<<B_ * N_, blk, 0, stream>>>(X, ln2_g + l * D_, ln2_b + l * D_, HB);
        mfma_gemm<false><<<dim3(12, 96), blk, 0, stream>>>(
            HB, f1T + (size_t)l * 2 * D_ * D_, f1_b + l * 2 * D_, nullptr, MID,
            B_ * N_, 2 * D_, D_, 1, 1);
        mfma_gemm<false><<<dim3(6, 96), blk, 0, stream>>>(
            MID, f2T + (size_t)l * 2 * D_ * D_, f2_b + l * D_, X, X,
            B_ * N_, D_, 2 * D_, 0, 0);
    }

    // ---- head + loss ----
    tokensel_kernel<<<dim3(B_ * NP_, 3), blk, 0, stream>>>(X, XS);
    mfma_gemm<false><<<dim3(6, 80), blk, 0, stream>>>(
        XS, h1T, h1_b, nullptr, PMID, B_ * NP_, D_, D_, 1, 1);
    mfma_gemm<true><<<dim3(3, 80), blk, 0, stream>>>(
        PMID, h2T, h2_b, nullptr, PRED, B_ * NP_, C_ * PL_, D_, 0, 0);
    loss_partial_kernel<<<B_ * NP_, blk, 0, stream>>>(PRED, patches, mask, PART);
    loss_final_kernel<<<1, blk, 0, stream>>>(PART, mask, (float*)d_out);
}